// Round 12
// baseline (408.048 us; speedup 1.0000x reference)
//
#include <hip/hip_runtime.h>
#include <hip/hip_fp16.h>
#include <math.h>

#define NREP 16
#define RDIM 16
#define NS   16
#define NC   6
#define H1   144
#define DBINS 64
#define TILE 4096
#define NBMAX 512     // max 256-row buckets supported (N <= 131072)
#define P2CAP 10240   // bucket LDS adj capacity; mean bucket = 4096 edges

static __device__ __forceinline__ float leaky(float v) { return v > 0.0f ? v : 0.01f * v; }

// ---------- fused: per-graph mean (LDS-binned) + LDS-aggregated bucket histogram ----------
__global__ void __launch_bounds__(256) k_gsum_bhist(
    const float* __restrict__ pos, const int* __restrict__ batch, int N,
    float* __restrict__ gsum, float* __restrict__ gcnt,
    const int* __restrict__ ei, int E, int* __restrict__ bhist) {
  int t = threadIdx.x;
  __shared__ int h[NBMAX];
  for (int i = t; i < NBMAX; i += 256) h[i] = 0;
  __syncthreads();
  int base = blockIdx.x * TILE;
  int lim = min(base + TILE, E);
  for (int j = base + t; j < lim; j += 256) atomicAdd(&h[ei[j] >> 8], 1);
  __syncthreads();
  for (int i = t; i < NBMAX; i += 256)
    if (h[i] > 0) atomicAdd(&bhist[i], h[i]);

  __shared__ float bx[320], by[320], bc[320];
  int start = blockIdx.x * 256;
  if (start >= N) return;
  int n = start + t;
  int b0 = batch[min(start, N - 1)];
  int span = batch[min(start + 255, N - 1)] - b0;
  bool useLds = (span < 320);
  if (useLds) {
    for (int i = t; i <= span; i += 256) { bx[i] = 0.f; by[i] = 0.f; bc[i] = 0.f; }
    __syncthreads();
    if (n < N) {
      int rb = batch[n] - b0;
      atomicAdd(&bx[rb], pos[2 * n + 0]);
      atomicAdd(&by[rb], pos[2 * n + 1]);
      atomicAdd(&bc[rb], 1.0f);
    }
    __syncthreads();
    for (int i = t; i <= span; i += 256) {
      if (bc[i] != 0.0f) {
        atomicAdd(&gsum[2 * (b0 + i) + 0], bx[i]);
        atomicAdd(&gsum[2 * (b0 + i) + 1], by[i]);
        atomicAdd(&gcnt[b0 + i], bc[i]);
      }
    }
  } else if (n < N) {
    int b = batch[n];
    atomicAdd(&gsum[2 * b + 0], pos[2 * n + 0]);
    atomicAdd(&gsum[2 * b + 1], pos[2 * n + 1]);
    atomicAdd(&gcnt[b], 1.0f);
  }
}

// ---------- center (elementwise) + block0: bucket-base scan ----------
__global__ void __launch_bounds__(256) k_center_bscan(
    const float* __restrict__ pos, const int* __restrict__ batch, int N, int E,
    const float* __restrict__ gsum, const float* __restrict__ gcnt,
    float* __restrict__ posc, float* __restrict__ cthn, float* __restrict__ sthn,
    const int* __restrict__ bhist, int* __restrict__ bbase, int* __restrict__ bcur, int NB) {
  int t = threadIdx.x;
  if (blockIdx.x == 0) {
    __shared__ int s[NBMAX];
    int v0 = (t < NB) ? bhist[t] : 0;
    int v1 = (t + 256 < NB) ? bhist[t + 256] : 0;
    s[t] = v0; s[t + 256] = v1;
    __syncthreads();
    for (int o = 1; o < NBMAX; o <<= 1) {
      int a0 = (t >= o) ? s[t - o] : 0;
      int a1 = s[t + 256 - o];
      __syncthreads();
      s[t] += a0; s[t + 256] += a1;
      __syncthreads();
    }
    if (t < NB)       { int ex = s[t] - v0;       bbase[t] = ex;       bcur[t] = ex; }
    if (t + 256 < NB) { int ex = s[t + 256] - v1; bbase[t + 256] = ex; bcur[t + 256] = ex; }
    if (t == 0) bbase[NB] = E;
  }
  int i = blockIdx.x * 256 + t;
  if (i < N) {
    int b = batch[i];
    float invc = 1.0f / fmaxf(gcnt[b], 1.0f);
    float px = pos[2 * i + 0] - gsum[2 * b + 0] * invc;
    float py = pos[2 * i + 1] - gsum[2 * b + 1] * invc;
    posc[2 * i + 0] = px;
    posc[2 * i + 1] = py;
    float r = sqrtf(px * px + py * py);
    if (r > 0.0f) { cthn[i] = px / r; sthn[i] = py / r; }
    else          { cthn[i] = 1.0f;  sthn[i] = 0.0f; }
  }
}

// ---------- CSR build pass 1: bucket-partition edges by row>>8 ----------
__global__ void __launch_bounds__(256) k_part1(
    const int* __restrict__ ei, int E,
    int* __restrict__ bcur, long long* __restrict__ ebuf) {
  __shared__ int hist[NBMAX], lofs[NBMAX], gbase[NBMAX], pc[NBMAX];
  __shared__ long long stg[TILE];
  __shared__ unsigned short bkt[TILE];
  int t = threadIdx.x;
  int base = blockIdx.x * TILE;
  int cntt = min(TILE, E - base);
  for (int i = t; i < NBMAX; i += 256) { hist[i] = 0; pc[i] = 0; }
  __syncthreads();
  int r[16], c[16];
#pragma unroll
  for (int i = 0; i < 16; i++) {
    int e = base + t + i * 256;
    r[i] = -1;
    if (e < E) {
      r[i] = ei[e];
      c[i] = ei[E + e];
      atomicAdd(&hist[r[i] >> 8], 1);
    }
  }
  __syncthreads();
  lofs[t] = hist[t]; lofs[t + 256] = hist[t + 256];
  __syncthreads();
  for (int o = 1; o < NBMAX; o <<= 1) {
    int a0 = (t >= o) ? lofs[t - o] : 0;
    int a1 = lofs[t + 256 - o];
    __syncthreads();
    lofs[t] += a0; lofs[t + 256] += a1;
    __syncthreads();
  }
  int e0 = lofs[t] - hist[t], e1 = lofs[t + 256] - hist[t + 256];
  __syncthreads();
  lofs[t] = e0; lofs[t + 256] = e1;
  __syncthreads();
  for (int i = t; i < NBMAX; i += 256)
    if (hist[i] > 0) gbase[i] = atomicAdd(&bcur[i], hist[i]);
  __syncthreads();
#pragma unroll
  for (int i = 0; i < 16; i++) {
    if (r[i] >= 0) {
      int b = r[i] >> 8;
      int l = lofs[b] + atomicAdd(&pc[b], 1);
      stg[l] = ((long long)r[i] << 32) | (unsigned int)c[i];
      bkt[l] = (unsigned short)b;
    }
  }
  __syncthreads();
  for (int j = t; j < cntt; j += 256) {
    int b = bkt[j];
    ebuf[gbase[b] + (j - lofs[b])] = stg[j];
  }
}

// ---------- lean pass 2: per-bucket row-hist + local scan (off/cnt/dhist) + in-LDS adj ----------
__global__ void __launch_bounds__(256) k_part2(
    const int* __restrict__ bbase, int N, int E,
    const long long* __restrict__ ebuf,
    int* __restrict__ off, int* __restrict__ cnt, int* __restrict__ dhist,
    int* __restrict__ adj) {
  __shared__ int lcnt[256], loff[256], lcur[256];
  __shared__ int lh[DBINS];
  __shared__ int ladj[P2CAP];
  int t = threadIdx.x;
  int b = blockIdx.x;
  int r0 = b << 8;
  int abeg = bbase[b];
  int aend = bbase[b + 1];
  int sz = aend - abeg;
  bool haveRow = (r0 + t < N);
  lcnt[t] = 0;
  if (t < DBINS) lh[t] = 0;
  __syncthreads();
  for (int j = abeg + t; j < aend; j += 256)
    atomicAdd(&lcnt[(int)(ebuf[j] >> 32) - r0], 1);
  __syncthreads();
  int v = lcnt[t];
  loff[t] = v;
  __syncthreads();
  for (int o = 1; o < 256; o <<= 1) {
    int u = (t >= o) ? loff[t - o] : 0;
    __syncthreads();
    loff[t] += u;
    __syncthreads();
  }
  int myoff = loff[t] - v;
  __syncthreads();
  loff[t] = myoff;
  lcur[t] = myoff;
  if (haveRow) {
    off[r0 + t] = abeg + myoff;
    cnt[r0 + t] = v;
    atomicAdd(&lh[min(v, DBINS - 1)], 1);
  }
  if (t == 0 && r0 + 256 >= N) off[N] = E;
  __syncthreads();
  if (t < DBINS && lh[t] > 0) atomicAdd(&dhist[t], lh[t]);
  if (sz <= P2CAP) {
    for (int j = abeg + t; j < aend; j += 256) {
      long long p = ebuf[j];
      int cl = (int)(unsigned int)(p & 0xffffffffLL);
      int rr = (int)(p >> 32) - r0;
      ladj[atomicAdd(&lcur[rr], 1)] = cl;
    }
    __syncthreads();
    for (int j = t; j < sz; j += 256) adj[abeg + j] = ladj[j];
  } else {
    for (int j = abeg + t; j < aend; j += 256) {
      long long p = ebuf[j];
      int cl = (int)(unsigned int)(p & 0xffffffffLL);
      int rr = (int)(p >> 32) - r0;
      adj[abeg + atomicAdd(&lcur[rr], 1)] = cl;
    }
  }
}

// ---------- fused node init + trig fill + layer-0 pre + degree-sort perm fill ----------
// permfill folded in: blocks < ceil(N/256) each handle one 256-node chunk (dhist/cnt are
// complete — k_part2 precedes). Saves a dispatch + launch gap; perm only needs to be a
// valid permutation (degree-grouped), block-local ordering is free.
__global__ void __launch_bounds__(256) k_init16(
    int N, const int* __restrict__ off, const int* __restrict__ adj,
    const float* __restrict__ posc, float2* __restrict__ spc,
    const float* __restrict__ Wer, const float* __restrict__ wse, const float* __restrict__ bse,
    const float* __restrict__ Wmix, const float* __restrict__ Ws1, const float* __restrict__ bs1,
    const float* __restrict__ Wgate, const float* __restrict__ bgate,
    const int* __restrict__ cnt, const int* __restrict__ dhist,
    int* __restrict__ dcur, int* __restrict__ perm,
    float* __restrict__ xr, float* __restrict__ xs, uint2* __restrict__ yzg) {
  int t = threadIdx.x;
  int nchunk = (N + 255) >> 8;
  if ((int)blockIdx.x < nchunk) {
    __shared__ int sd[DBINS], lh[DBINS], base[DBINS];
    int dv = 0;
    if (t < DBINS) { dv = dhist[t]; sd[t] = dv; lh[t] = 0; }
    __syncthreads();
    for (int o = 1; o < DBINS; o <<= 1) {
      int u = (t >= o && t < DBINS) ? sd[t - o] : 0;
      __syncthreads();
      if (t < DBINS) sd[t] += u;
      __syncthreads();
    }
    int i = blockIdx.x * 256 + t;
    int b = 0, lr = 0;
    if (i < N) {
      b = min(cnt[i], DBINS - 1);
      lr = atomicAdd(&lh[b], 1);
    }
    __syncthreads();
    if (t < DBINS && lh[t] > 0) base[t] = (sd[t] - dv) + atomicAdd(&dcur[t], lh[t]);
    __syncthreads();
    if (i < N) perm[base[b] + lr] = i;
  }

  int idx = blockIdx.x * 256 + t;
  int n = idx >> 4, r = idx & 15;
  if (n >= N) return;
  int a = off[n], b = off[n + 1];
  float px = posc[2 * n + 0], py = posc[2 * n + 1];
  float C = 0.f, S = 0.f, D = 0.f;
  for (int k = a + r; k < b; k += 16) {
    int cl = adj[k];
    float dx = px - posc[2 * cl + 0];
    float dy = py - posc[2 * cl + 1];
    float d = sqrtf(dx * dx + dy * dy);
    float sp, cp;
    sincospif(d, &sp, &cp);
    float spp = 1.41421356237309515f * sp / (d + 1e-8f);
    spc[k] = make_float2(spp, 2.0f * cp);
    if (d > 0.0f) {
      float inv = 1.0f / d;
      C += dx * inv;
      S += dy * inv;
    } else {
      C += 1.0f;
    }
    D += d;
  }
#pragma unroll
  for (int o = 1; o < 16; o <<= 1) {
    C += __shfl_xor(C, o, 16);
    S += __shfl_xor(S, o, 16);
    D += __shfl_xor(D, o, 16);
  }
  float id = 1.0f / fmaxf((float)(b - a), 1.0f);
  C *= id; S *= id;
  float dm = D * id;
  float w0 = Wer[2 * r], w1 = Wer[2 * r + 1];
  float2 x;
  x.x = C * w0 - S * w1;
  x.y = S * w0 + C * w1;
  ((float2*)xr)[(size_t)n * 16 + r] = x;
  float s_new = leaky(dm * wse[r] + bse[r]);
  xs[(size_t)n * 16 + r] = s_new;

  float wmxn[16], wsan[16], wgtn[16];
#pragma unroll
  for (int q = 0; q < 16; q++) wmxn[q] = Wmix[r * 16 + q];
#pragma unroll
  for (int q = 0; q < 16; q++) wsan[q] = Ws1[q * 16 + r];
#pragma unroll
  for (int q = 0; q < 16; q++) wgtn[q] = Wgate[q * 16 + r];
  float y0 = 0.f, y1 = 0.f;
  float z = bs1[r], gtn = bgate[r];
#pragma unroll
  for (int j = 0; j < 16; j++) {
    float xj0 = __shfl(x.x, j, 16);
    float xj1 = __shfl(x.y, j, 16);
    float sj  = __shfl(s_new, j, 16);
    y0 += wmxn[j] * xj0;
    y1 += wmxn[j] * xj1;
    z  += wsan[j] * sj;
    gtn += wgtn[j] * sj;
  }
  gtn = 1.0f / (1.0f + __expf(-gtn));
  __half2 hA = __floats2half2_rn(y0, y1);
  __half2 hB = __floats2half2_rn(z, gtn);
  uint2 w2;
  w2.x = *(unsigned int*)&hA;
  w2.y = *(unsigned int*)&hB;
  yzg[(size_t)n * 16 + r] = w2;
}

// ---------- EqBlock layer + fused next-layer pre (r9 scalar form — proven 70us) ----------
// r10 post-mortem: packed v_pk_fma halved VALU issue (VALUBusy 75.8->50.5) but dur ROSE
// 70->72.6 (VGPR 40->56): the kernel's floor is the yzg gather (128B/edge over a 12.8MB
// array spanning >4MB XCD L2), not VALU issue. Scalar form dominates — keep it.
__global__ void __launch_bounds__(256) k_layer(
    int N, const int* __restrict__ off,
    const int* __restrict__ adj, const float2* __restrict__ spc,
    const uint2* __restrict__ yzg, const int* __restrict__ perm,
    const float* __restrict__ Wg, const float* __restrict__ bg,
    const float* __restrict__ Ws1,   // this layer; demb rows are 16..31
    float* xr, float* xs,
    int write_next, uint2* __restrict__ yzg_out,
    const float* __restrict__ Wmixn, const float* __restrict__ Ws1n,
    const float* __restrict__ bs1n,
    const float* __restrict__ Wgaten, const float* __restrict__ bgaten) {
  int idx = blockIdx.x * 256 + threadIdx.x;
  int g = idx >> 4, r = idx & 15;
  if (g >= N) return;
  int n = perm[g];
  float wg[16], ws[16];
#pragma unroll
  for (int q = 0; q < 16; q++) wg[q] = Wg[q * 16 + r];
#pragma unroll
  for (int q = 0; q < 16; q++) ws[q] = Ws1[(16 + q) * 16 + r];
  float bgr = bg[r];

  int a = off[n], bnd = off[n + 1];
  float acc0 = 0.f, acc1 = 0.f, accs = 0.f;
  if (a < bnd) {
    int last = bnd - 1;
    int    c0 = adj[a];               float2 p0 = spc[a];
    int    c1 = adj[min(a + 1, last)]; float2 p1 = spc[min(a + 1, last)];
    int    cn = adj[min(a + 2, last)]; float2 p2 = spc[min(a + 2, last)];
    uint2 Y0 = yzg[(c0 << 4) + r];
    uint2 Y1 = yzg[(c1 << 4) + r];
    int k = a;
    for (; k + 3 < bnd; k++) {
      int c3 = adj[k + 3];
      float2 p3 = spc[k + 3];
      uint2 Y2 = yzg[(cn << 4) + r];
      float skm1 = 0.f, sk = p0.x, c2 = p0.y;
      float g1 = bgr, dot = 0.f;
#pragma unroll
      for (int q = 0; q < RDIM; q++) {
        g1  = __builtin_fmaf(sk, wg[q], g1);
        dot = __builtin_fmaf(sk, ws[q], dot);
        float sn = __builtin_fmaf(c2, sk, -skm1);
        skm1 = sk; sk = sn;
      }
      float2 f01 = __half22float2(*(__half2*)&Y0.x);
      float2 fzg = __half22float2(*(__half2*)&Y0.y);
      acc0 = __builtin_fmaf(g1, f01.x, acc0);
      acc1 = __builtin_fmaf(g1, f01.y, acc1);
      accs += leaky(dot + fzg.x);
      c0 = c1; p0 = p1; c1 = cn; p1 = p2; cn = c3; p2 = p3; Y0 = Y1; Y1 = Y2;
    }
    for (; k < bnd; k++) {
      uint2 Y2 = Y1;
      if (k + 2 < bnd) Y2 = yzg[(cn << 4) + r];
      float skm1 = 0.f, sk = p0.x, c2 = p0.y;
      float g1 = bgr, dot = 0.f;
#pragma unroll
      for (int q = 0; q < RDIM; q++) {
        g1  = __builtin_fmaf(sk, wg[q], g1);
        dot = __builtin_fmaf(sk, ws[q], dot);
        float sn = __builtin_fmaf(c2, sk, -skm1);
        skm1 = sk; sk = sn;
      }
      float2 f01 = __half22float2(*(__half2*)&Y0.x);
      float2 fzg = __half22float2(*(__half2*)&Y0.y);
      acc0 = __builtin_fmaf(g1, f01.x, acc0);
      acc1 = __builtin_fmaf(g1, f01.y, acc1);
      accs += leaky(dot + fzg.x);
      c0 = c1; p0 = p1; c1 = cn; p1 = p2; Y0 = Y1; Y1 = Y2;
    }
  }
  float id = 1.0f / fmaxf((float)(bnd - a), 1.0f);
  uint2 Yg = yzg[(n << 4) + r];
  float gt = __half22float2(*(__half2*)&Yg.y).y;
  float2* xr2 = (float2*)xr;
  float2 x = xr2[(n << 4) + r];
  x.x += acc0 * id * gt;
  x.y += acc1 * id * gt;
  xr2[(n << 4) + r] = x;
  float s_new = xs[(n << 4) + r] + accs * id;
  xs[(n << 4) + r] = s_new;

  if (write_next) {
    float wmxn[16], wsan[16], wgtn[16];
#pragma unroll
    for (int q = 0; q < 16; q++) wmxn[q] = Wmixn[r * 16 + q];
#pragma unroll
    for (int q = 0; q < 16; q++) wsan[q] = Ws1n[q * 16 + r];
#pragma unroll
    for (int q = 0; q < 16; q++) wgtn[q] = Wgaten[q * 16 + r];
    float y0 = 0.f, y1 = 0.f;
    float z = bs1n[r], gtn = bgaten[r];
#pragma unroll
    for (int j = 0; j < 16; j++) {
      float xj0 = __shfl(x.x, j, 16);
      float xj1 = __shfl(x.y, j, 16);
      float sj  = __shfl(s_new, j, 16);
      y0 += wmxn[j] * xj0;
      y1 += wmxn[j] * xj1;
      z  += wsan[j] * sj;
      gtn += wgtn[j] * sj;
    }
    gtn = 1.0f / (1.0f + __expf(-gtn));
    __half2 hA = __floats2half2_rn(y0, y1);
    __half2 hB = __floats2half2_rn(z, gtn);
    uint2 w2;
    w2.x = *(unsigned int*)&hA;
    w2.y = *(unsigned int*)&hB;
    yzg_out[(n << 4) + r] = w2;
  }
}

// ---------- final rotate-out + MLP + binned graph sum (unchanged) ----------
__global__ void __launch_bounds__(128) k_final(
    int N, const float* __restrict__ xr, const float* __restrict__ xs,
    const float* __restrict__ cthn, const float* __restrict__ sthn,
    const int* __restrict__ batch,
    const float* __restrict__ W1, const float* __restrict__ b1,
    const float* __restrict__ W2, const float* __restrict__ b2,
    float* __restrict__ out) {
  __shared__ float obin[320 * 6];
  int t = threadIdx.x;
  int start = blockIdx.x * 128;
  int n = start + t;
  int b0 = batch[min(start, N - 1)];
  int span = batch[min(start + 127, N - 1)] - b0;
  bool useLds = (span < 320);
  if (useLds) for (int i = t; i < (span + 1) * 6; i += 128) obin[i] = 0.f;
  __syncthreads();

  float u[NC];
  bool act = (n < N);
  if (act) {
    float xc[48];
    const float4* xs4 = (const float4*)(xs + (size_t)n * NS);
#pragma unroll
    for (int j = 0; j < 4; j++) {
      float4 v = xs4[j];
      xc[4 * j + 0] = v.x; xc[4 * j + 1] = v.y; xc[4 * j + 2] = v.z; xc[4 * j + 3] = v.w;
    }
    float c = cthn[n], s = sthn[n];
    const float4* xr4 = (const float4*)(xr + (size_t)n * 32);
#pragma unroll
    for (int j = 0; j < 8; j++) {
      float4 v = xr4[j];
      xc[16 + 4 * j + 0] = c * v.x - s * v.y;
      xc[16 + 4 * j + 1] = s * v.x + c * v.y;
      xc[16 + 4 * j + 2] = c * v.z - s * v.w;
      xc[16 + 4 * j + 3] = s * v.z + c * v.w;
    }
#pragma unroll
    for (int q = 0; q < NC; q++) u[q] = b2[q];
    for (int h = 0; h < H1; h += 4) {
      float a0 = b1[h + 0], a1 = b1[h + 1], a2 = b1[h + 2], a3 = b1[h + 3];
#pragma unroll
      for (int q = 0; q < 48; q++) {
        float4 w = *(const float4*)(W1 + (size_t)q * H1 + h);
        float x = xc[q];
        a0 = __builtin_fmaf(x, w.x, a0);
        a1 = __builtin_fmaf(x, w.y, a1);
        a2 = __builtin_fmaf(x, w.z, a2);
        a3 = __builtin_fmaf(x, w.w, a3);
      }
      a0 = leaky(a0); a1 = leaky(a1); a2 = leaky(a2); a3 = leaky(a3);
#pragma unroll
      for (int q = 0; q < NC; q++)
        u[q] += a0 * W2[(h + 0) * 6 + q] + a1 * W2[(h + 1) * 6 + q]
              + a2 * W2[(h + 2) * 6 + q] + a3 * W2[(h + 3) * 6 + q];
    }
  }
  if (useLds) {
    if (act) {
      int rb = batch[n] - b0;
#pragma unroll
      for (int q = 0; q < NC; q++) atomicAdd(&obin[rb * 6 + q], u[q]);
    }
    __syncthreads();
    for (int i = t; i < (span + 1) * 6; i += 128) atomicAdd(&out[b0 * 6 + i], obin[i]);
  } else if (act) {
    int b = batch[n];
#pragma unroll
    for (int q = 0; q < NC; q++) atomicAdd(&out[b * 6 + q], u[q]);
  }
}

extern "C" void kernel_launch(void* const* d_in, const int* in_sizes, int n_in,
                              void* d_out, int out_size, void* d_ws, size_t ws_size,
                              hipStream_t stream) {
  const float* pos   = (const float*)d_in[0];
  const float* Wer   = (const float*)d_in[1];
  const float* wse   = (const float*)d_in[2];
  const float* bse   = (const float*)d_in[3];
  const float* Wg    = (const float*)d_in[4];
  const float* bg    = (const float*)d_in[5];
  const float* Wmix  = (const float*)d_in[6];
  const float* Wgate = (const float*)d_in[7];
  const float* bgate = (const float*)d_in[8];
  const float* Ws1   = (const float*)d_in[9];
  const float* bs1   = (const float*)d_in[10];
  const float* W1    = (const float*)d_in[11];
  const float* b1    = (const float*)d_in[12];
  const float* W2    = (const float*)d_in[13];
  const float* b2    = (const float*)d_in[14];
  const int*   ei    = (const int*)d_in[15];
  const int*   batch = (const int*)d_in[16];
  float* out = (float*)d_out;

  int N = in_sizes[0] / 2;
  int E = in_sizes[15] / 2;
  int G = out_size / NC;
  int NB = (N + 255) / 256;   // 256-row buckets (requires NB <= NBMAX)

  // ---- workspace layout (~67 MB; ebuf aliases spc) ----
  float* W = (float*)d_ws;
  size_t o = 0;
  float* gsum   = W + o; o += (size_t)2 * G;
  float* gcnt   = W + o; o += (size_t)G;
  int*   bhist  = (int*)(W + o); o += (size_t)NBMAX;
  int*   dhist  = (int*)(W + o); o += (size_t)DBINS;
  int*   dcur   = (int*)(W + o); o += (size_t)DBINS;
  size_t zero_bytes = o * 4;
  o = (o + 3) & ~(size_t)3;
  float* posc   = W + o; o += (size_t)2 * N;
  float* cthn   = W + o; o += (size_t)N;
  float* sthn   = W + o; o += (size_t)N;
  int*   off    = (int*)(W + o); o += (size_t)N + 1; o = (o + 3) & ~(size_t)3;
  int*   bbase  = (int*)(W + o); o += (size_t)NBMAX + 1;
  int*   bcur   = (int*)(W + o); o += (size_t)NBMAX;
  int*   cnt    = (int*)(W + o); o += (size_t)N;
  int*   perm   = (int*)(W + o); o += (size_t)N; o = (o + 3) & ~(size_t)3;
  int*   adj    = (int*)(W + o); o += (size_t)E; o = (o + 1) & ~(size_t)1;
  float2* spc   = (float2*)(W + o); o += (size_t)2 * E;
  long long* ebuf = (long long*)spc;   // ALIAS: ebuf dead after k_part2; spc written by k_init16
  uint2* yzgA   = (uint2*)(W + o); o += (size_t)32 * N;
  uint2* yzgB   = (uint2*)(W + o); o += (size_t)32 * N;
  float* xr     = W + o; o += (size_t)N * 32;
  float* xs     = W + o; o += (size_t)N * 16;
  (void)ws_size;

  hipMemsetAsync(d_ws, 0, zero_bytes, stream);
  hipMemsetAsync(d_out, 0, (size_t)out_size * 4, stream);

  int nbN  = (N + 255) / 256;
  int nbT  = (E + TILE - 1) / TILE;
  int nbG  = nbT > nbN ? nbT : nbN;
  int nbN16 = ((size_t)N * 16 + 255) / 256;
  int nbF  = (N + 127) / 128;

  k_gsum_bhist<<<nbG, 256, 0, stream>>>(pos, batch, N, gsum, gcnt, ei, E, bhist);
  k_center_bscan<<<nbN, 256, 0, stream>>>(pos, batch, N, E, gsum, gcnt,
                                          posc, cthn, sthn, bhist, bbase, bcur, NB);
  k_part1<<<nbT, 256, 0, stream>>>(ei, E, bcur, ebuf);
  k_part2<<<NB, 256, 0, stream>>>(bbase, N, E, ebuf, off, cnt, dhist, adj);
  k_init16<<<nbN16, 256, 0, stream>>>(N, off, adj, posc, spc, Wer, wse, bse,
                                      Wmix, Ws1, bs1, Wgate, bgate,
                                      cnt, dhist, dcur, perm,
                                      xr, xs, yzgA);

  // layer 0: read A, write B (fused pre for layer 1)
  k_layer<<<nbN16, 256, 0, stream>>>(N, off, adj, spc, yzgA, perm,
                                     Wg, bg, Ws1, xr, xs,
                                     1, yzgB,
                                     Wmix + 256, Ws1 + 512, bs1 + 16, Wgate + 256, bgate + 16);
  // layer 1: read B, write A (fused pre for layer 2)
  k_layer<<<nbN16, 256, 0, stream>>>(N, off, adj, spc, yzgB, perm,
                                     Wg + 256, bg + 16, Ws1 + 512, xr, xs,
                                     1, yzgA,
                                     Wmix + 512, Ws1 + 1024, bs1 + 32, Wgate + 512, bgate + 32);
  // layer 2: read A, no next
  k_layer<<<nbN16, 256, 0, stream>>>(N, off, adj, spc, yzgA, perm,
                                     Wg + 512, bg + 32, Ws1 + 1024, xr, xs,
                                     0, yzgB,
                                     Wmix, Ws1, bs1, Wgate, bgate);

  k_final<<<nbF, 128, 0, stream>>>(N, xr, xs, cthn, sthn, batch, W1, b1, W2, b2, out);
}